// Round 7
// baseline (226.046 us; speedup 1.0000x reference)
//
#include <hip/hip_runtime.h>

// GRAPE step collapse: all steps rotate about X, so the scan == one rotation by
// Theta = sum(a_k) * (DT/2).
//   out_real0 = c*r0 + s*i1    out_imag0 = c*i0 - s*r1
//   out_real1 = c*r1 + s*i0    out_imag1 = c*i1 - s*r0
// Output layout: [real0 | real1 | imag0 | imag1], each segment B floats.
//
// Pair decoupling (R3): pair h=0: (r0,i1)->(out0,out3); h=1: (r1,i0)->(out1,out2).
// Each half-grid is a pure 2-load/2-store stream.
//
// R6 (kept): NON-TEMPORAL LOADS — first real win, grape ~79 -> ~64us
// (bench 240 -> 225.7; grape left the top-5 entirely). Model: input
// read-fills no longer allocate in the poison-dirtied LLC, killing the
// dirty-victim writeback stream those allocations forced.
// R7 single change: + NON-TEMPORAL STORES. Remaining ~20us over pure-stream
// cost fits the OUTPUT's write-allocate victim traffic (131R+131W+~128
// victim-WB = 390MB @6.3TB/s = 62us = observed). R1/R5 tested store-nt only
// WITHOUT nt loads (read-victim stream dominated, masking it). If honored:
// 262MB pure streaming ~= 42-50us. If bench stays ~225: revert & declare.
// History: R0 81; R1 nt-store 87; R2 persist 87; R3 pair 79; R4 persist+u2 82;
// R5 sc0sc1nt 80; R6 nt-load ~64 (bench 225.7).

typedef float f4 __attribute__((ext_vector_type(4)));

__global__ __launch_bounds__(256) void grape_kernel(
    const float* __restrict__ amps, int nsteps,
    const float* __restrict__ sreal, const float* __restrict__ simag,
    float* __restrict__ out, long long B, long long blocks_per_half) {
    // Theta is wave-uniform; a handful of scalar cached loads, negligible.
    float theta = 0.0f;
    for (int k = 0; k < nsteps; ++k) theta += amps[k];
    theta *= (1.0f / (float)nsteps) * 0.5f;  // DT/2 with GATE_TIME=1.0
    const float c = cosf(theta);
    const float s = sinf(theta);

    const long long h = (blockIdx.x >= blocks_per_half) ? 1 : 0;
    const long long v = ((long long)blockIdx.x - h * blocks_per_half) * blockDim.x
                        + threadIdx.x;
    const long long j = v * 4;

    const float* __restrict__ x = sreal + h * B;        // r0 or r1
    const float* __restrict__ y = simag + (1 - h) * B;  // i1 or i0
    float* __restrict__ outr = out + h * B;             // out0 or out1
    float* __restrict__ outi = out + (3 - h) * B;       // out3 or out2

    if (j + 3 < B) {
        const f4 xv = __builtin_nontemporal_load((const f4*)(x + j));
        const f4 yv = __builtin_nontemporal_load((const f4*)(y + j));
        __builtin_nontemporal_store(c * xv + s * yv, (f4*)(outr + j));
        __builtin_nontemporal_store(c * yv - s * xv, (f4*)(outi + j));
    } else if (j < B) {
        for (long long t = j; t < B; ++t) {
            const float xs = x[t], ys = y[t];
            outr[t] = c * xs + s * ys;
            outi[t] = c * ys - s * xs;
        }
    }
}

extern "C" void kernel_launch(void* const* d_in, const int* in_sizes, int n_in,
                              void* d_out, int out_size, void* d_ws, size_t ws_size,
                              hipStream_t stream) {
    const float* amps  = (const float*)d_in[0];
    const float* sreal = (const float*)d_in[1];
    const float* simag = (const float*)d_in[2];
    float* out = (float*)d_out;

    int nsteps = in_sizes[0];
    long long B = (long long)in_sizes[1] / 2;  // state_real is [2, B]

    const int block = 256;
    long long nv = (B + 3) / 4;                       // f4 chunks per half
    long long blocks_per_half = (nv + block - 1) / block;
    long long grid = 2 * blocks_per_half;             // one-shot (best: R3/R6)

    grape_kernel<<<(dim3)(unsigned)grid, block, 0, stream>>>(
        amps, nsteps, sreal, simag, out, B, blocks_per_half);
}